// Round 14
// baseline (669.935 us; speedup 1.0000x reference)
//
#include <hip/hip_runtime.h>

#define S_LEN 2048
#define BATCH 2
#define HID 4096
#define NH 32
#define NKV 8
#define DH 128
#define MROWS (BATCH*S_LEN)   // 4096
#define QKV_N 6144

typedef unsigned short u16;
typedef unsigned int u32;
typedef __bf16 bf16x8 __attribute__((ext_vector_type(8)));
typedef float f32x4 __attribute__((ext_vector_type(4)));
typedef u16 u16x8 __attribute__((ext_vector_type(8)));

__device__ __forceinline__ u16 f2bf(float f) {           // round-half-up (2 insts)
  union { float f; u32 u; } v; v.f = f;
  return (u16)((v.u + 0x8000u) >> 16);
}
__device__ __forceinline__ float bf2f(u16 h) {
  union { u32 u; float f; } v; v.u = ((u32)h) << 16;
  return v.f;
}
__device__ __forceinline__ u32 cvtpk(float a, float b) { // packs bf16(a)|bf16(b)<<16
  u32 r;
  asm("v_cvt_pk_bf16_f32 %0, %1, %2" : "=v"(r) : "v"(a), "v"(b));
  return r;
}
__device__ __forceinline__ void async16(const void* g, void* l) {
  __builtin_amdgcn_global_load_lds(
      (const __attribute__((address_space(1))) u32*)g,
      (__attribute__((address_space(3))) u32*)l, 16, 0, 0);
}
__device__ __forceinline__ f32x4 mfma16(bf16x8 a, bf16x8 b, f32x4 c) {
  return __builtin_amdgcn_mfma_f32_16x16x32_bf16(a, b, c, 0, 0, 0);
}

#define BAR()    __builtin_amdgcn_s_barrier()
#define LGKM0()  asm volatile("s_waitcnt lgkmcnt(0)" ::: "memory")
#define PRIO(x)  __builtin_amdgcn_s_setprio(x)

// ---------------- fp32 -> bf16 conversion ----------------
__global__ __launch_bounds__(256) void cvt_f32_bf16(const float* __restrict__ in,
                                                    u16* __restrict__ out, int n) {
  int i0 = (blockIdx.x * 256 + threadIdx.x) * 8;
  if (i0 >= n) return;
  float4 a = *(const float4*)(in + i0);
  float4 b = *(const float4*)(in + i0 + 4);
  u16x8 r;
  r[0]=f2bf(a.x); r[1]=f2bf(a.y); r[2]=f2bf(a.z); r[3]=f2bf(a.w);
  r[4]=f2bf(b.x); r[5]=f2bf(b.y); r[6]=f2bf(b.z); r[7]=f2bf(b.w);
  *(u16x8*)(out + i0) = r;
}

// ---------------- 256x256 NT bf16 GEMM, r14: 4 FAT waves (gemm4w) ----------
// Diagnosis (r5-r13): per CU per K-tile-64, the 8-wave structure issues 192
// ds_read_b128 vs 620cy of MFMA -> LDS-read-port bound at ~37% MfmaUtil;
// panel re-read traffic = wave_count x panel bytes (shape-independent, r12).
// Fix: 4 waves (2x2), each owns 128x128 -> 128 reads per K-64 (MFMA:read
// 4.0 vs 2.67). BK=32 (one 16x16x32 K-step per tile); quad-buffered LDS
// (mod-4, 4 x (A16KB+B16KB) = 128KB); register ping-pong X/Y so rd(k+1)
// overlaps MFMA(k); ONE barrier per K-tile-32 (half r11's rate).
// LDS packing: tile [256 rows][32 k] stored as [128 LDS-rows][64 u16]:
// LDS row R = {row 2R | row 2R+1}, 8 chunks of 16B; phys chunk = logical ^
// (R&7) (verified-zero-conflict family: 64 lanes -> 8 lanes/chunk-slot).
// Read: row ra, k-octet hi -> R=ra>>1, logical=(ra&1)*4+hi.
// Hazard ledger: body k = {rd(k+1 from buf (k+1)&3) | MFMA(k on regs) |
// stage(k+4 -> buf k&3) | vmcnt(16) | lgkmcnt(0) | BAR}.
//  - stage->buf k&3: rd(k) was drained by lgkmcnt(0) before the PREVIOUS
//    barrier (all waves) -> no read-write race.
//  - rd(k+1): stage(k+1) (issued body k-3) confirmed by vmcnt(16) at end of
//    body k-1 (keeps only sets k+3,k+2) + barrier -> landed for all waves.
//  - vmcnt(16) drains 2-body-old stages (~900cy) -> near-zero stall, never 0.
__global__ __launch_bounds__(256, 1) void gemm4w(
    const u16* __restrict__ A, const u16* __restrict__ B, u16* __restrict__ Cout,
    int M, int N, int K, int XC, int SR, int SC) {
  __shared__ u16 Ab[4][128 * 64];      // [buf mod4][packed 128x64]
  __shared__ u16 Bb[4][128 * 64];
  const int NKT = K >> 5;              // K-tiles of 32 (even, >= 8)
  int bid = (int)blockIdx.x;
  int xcd = bid & 7, l = bid >> 3;     // 2-D XCD sub-grid map
  int tm = (xcd / XC) * SR + l / SC;
  int tn = (xcd % XC) * SC + l % SC;
  int m0 = tm << 8, n0 = tn << 8;
  int t = threadIdx.x;
  int w = t >> 6, lane = t & 63, lo = lane & 15, hi = lane >> 4;
  int wm = w >> 1, wn = w & 1;

  // staging source precompute (inverse swizzle): set i covers chunk id=i*256+t
  int srcrow[4], srckk[4];
#pragma unroll
  for (int i = 0; i < 4; ++i) {
    int id = (i << 8) + t;
    int R = id >> 3, c = id & 7, sc = c ^ (R & 7);
    srcrow[i] = (R << 1) + (sc >> 2);
    srckk[i] = (sc & 3) << 3;
  }
  // fragment read offsets (u16 index within one 16KB buf)
  int offA[8], offB[8];
#pragma unroll
  for (int f = 0; f < 8; ++f) {
    int ra = (wm << 7) + (f << 4) + lo;
    int R = ra >> 1, c = ((((ra & 1) << 2) + hi)) ^ (R & 7);
    offA[f] = (R << 6) + (c << 3);
    int rb = (wn << 7) + (f << 4) + lo;
    int R2 = rb >> 1, c2 = ((((rb & 1) << 2) + hi)) ^ (R2 & 7);
    offB[f] = (R2 << 6) + (c2 << 3);
  }

  auto stage = [&](int kt, int buf) {          // 8 gloads: A 4 + B 4
    const u16* As = A + (size_t)m0 * K + (kt << 5);
    const u16* Bs = B + (size_t)n0 * K + (kt << 5);
#pragma unroll
    for (int i = 0; i < 4; ++i) {
      async16(As + (size_t)srcrow[i] * K + srckk[i],
              (char*)&Ab[buf][0] + (((i << 8) + t) << 4));
      async16(Bs + (size_t)srcrow[i] * K + srckk[i],
              (char*)&Bb[buf][0] + (((i << 8) + t) << 4));
    }
  };

  f32x4 acc[8][8];
  const f32x4 fz = {0.f, 0.f, 0.f, 0.f};
#pragma unroll
  for (int i = 0; i < 8; ++i)
#pragma unroll
    for (int j = 0; j < 8; ++j) acc[i][j] = fz;
  bf16x8 aX[8], bX[8], aY[8], bY[8];

  auto rd = [&](int buf, bf16x8 (&aT)[8], bf16x8 (&bT)[8]) {  // 16 ds_read_b128
    const u16* Abase = &Ab[buf][0];
    const u16* Bbase = &Bb[buf][0];
#pragma unroll
    for (int f = 0; f < 8; ++f) {
      aT[f] = *(const bf16x8*)(Abase + offA[f]);
      bT[f] = *(const bf16x8*)(Bbase + offB[f]);
    }
  };
  auto MM = [&](bf16x8 (&aT)[8], bf16x8 (&bT)[8]) {           // 64 MFMA
#pragma unroll
    for (int mf = 0; mf < 8; ++mf)
#pragma unroll
      for (int nf = 0; nf < 8; ++nf)
        acc[mf][nf] = mfma16(aT[mf], bT[nf], acc[mf][nf]);
  };

  // prologue: stage tiles 0-3; drain tile0 (keep 24 newest); read tile0; sync
  stage(0, 0); stage(1, 1); stage(2, 2); stage(3, 3);
  asm volatile("s_waitcnt vmcnt(24)" ::: "memory");
  BAR();
  rd(0, aX, bX);
  LGKM0();
  BAR();

  const int NJ = NKT >> 1;
  for (int j = 0; j < NJ; ++j) {
    int k0 = j << 1, k1 = k0 + 1;
    {  // body k0: compute X, prefetch-read into Y
      rd((k0 + 1) & 3, aY, bY);
      PRIO(1);
      MM(aX, bX);
      PRIO(0);
      int ks = k0 + 4; if (ks >= NKT) ks -= NKT;   // wrap: redundant, uniform
      stage(ks, k0 & 3);
      asm volatile("s_waitcnt vmcnt(16)" ::: "memory");
      LGKM0();
      BAR();
    }
    {  // body k1: compute Y, prefetch-read into X
      rd((k1 + 1) & 3, aX, bX);
      PRIO(1);
      MM(aY, bY);
      PRIO(0);
      int ks = k1 + 4; if (ks >= NKT) ks -= NKT;
      stage(ks, k1 & 3);
      asm volatile("s_waitcnt vmcnt(16)" ::: "memory");
      LGKM0();
      BAR();
    }
  }

  // epilogue: C layout col=lane&15 (lo), rows hi*4+r per 16x16 frag
#pragma unroll
  for (int mf = 0; mf < 8; ++mf)
#pragma unroll
    for (int nf = 0; nf < 8; ++nf)
#pragma unroll
      for (int r = 0; r < 4; ++r) {
        int row = m0 + (wm << 7) + (mf << 4) + (hi << 2) + r;
        int col = n0 + (wn << 7) + (nf << 4) + lo;
        Cout[(size_t)row * N + col] = f2bf(acc[mf][nf][r]);
      }
}

// ---------------- 256x256 NT bf16 GEMM (r11 version, O-proj control) -------
template<int OUT_BF16>
__global__ __launch_bounds__(512, 2) void gemm256(
    const u16* __restrict__ A, const u16* __restrict__ B, void* __restrict__ Cout,
    int M, int N, int K, int XC, int SR, int SC) {
  __shared__ u16 As[2][2][64 * 128];
  __shared__ u16 Bs[2][2][64 * 128];
  const int NKT = K >> 6;
  int bid = (int)blockIdx.x;
  int xcd = bid & 7, l = bid >> 3;
  int tm = (xcd / XC) * SR + l / SC;
  int tn = (xcd % XC) * SC + l % SC;
  int m0 = tm << 8, n0 = tn << 8;
  int t = threadIdx.x;
  int w = t >> 6, lane = t & 63, lo = lane & 15, hi = lane >> 4;
  int wm = w >> 2, wn = w & 3;
  int rbb = (wn & 1) << 6;

  int srow = (w << 3) + (lane >> 3);
  int scol = (lane & 7) << 3;

  auto stageA = [&](int kt, int buf, int h) {
#pragma unroll
    for (int c2 = 0; c2 < 2; ++c2) {
      int row = (c2 << 6) + srow;
      int col = scol ^ ((row & 7) << 3);
      async16(A + (size_t)(m0 + (h << 7) + row) * K + (kt << 6) + col,
              (char*)&As[buf][h][0] + (c2 << 13) + (w << 10));
    }
  };
  auto stageB = [&](int kt, int buf, int h) {
#pragma unroll
    for (int c2 = 0; c2 < 2; ++c2) {
      int row = (c2 << 6) + srow;
      int col = scol ^ ((row & 7) << 3);
      async16(B + (size_t)(n0 + (h << 7) + row) * K + (kt << 6) + col,
              (char*)&Bs[buf][h][0] + (c2 << 13) + (w << 10));
    }
  };

  const f32x4 fz = {0.f, 0.f, 0.f, 0.f};
  f32x4 acc[8][4];
#pragma unroll
  for (int i = 0; i < 8; ++i)
#pragma unroll
    for (int j = 0; j < 4; ++j) acc[i][j] = fz;
  bf16x8 af[4][2], bf0[2][2], bf1[2][2];

  auto rdA = [&](int c, int half, bf16x8 (&dst)[4][2]) {
    const u16* Ab = &As[c][wm][0];
#pragma unroll
    for (int mf = 0; mf < 4; ++mf)
#pragma unroll
      for (int ks = 0; ks < 2; ++ks) {
        int ra = (half << 6) + (mf << 4) + lo;
        dst[mf][ks] = *(const bf16x8*)(Ab + (ra << 6) +
                      (((ks << 5) + (hi << 3)) ^ ((ra & 7) << 3)));
      }
  };
  auto rdB = [&](int c, int bfrag, bf16x8 (&dst)[2][2]) {
    const u16* Bb = &Bs[c][wn >> 1][0];
#pragma unroll
    for (int nf = 0; nf < 2; ++nf)
#pragma unroll
      for (int ks = 0; ks < 2; ++ks) {
        int rb = rbb + (bfrag << 5) + (nf << 4) + lo;
        dst[nf][ks] = *(const bf16x8*)(Bb + (rb << 6) +
                      (((ks << 5) + (hi << 3)) ^ ((rb & 7) << 3)));
      }
  };
  auto MM = [&](bf16x8 (&a)[4][2], bf16x8 (&b)[2][2], int mo, int no) {
#pragma unroll
    for (int mf = 0; mf < 4; ++mf)
#pragma unroll
      for (int nf = 0; nf < 2; ++nf)
#pragma unroll
        for (int ks = 0; ks < 2; ++ks)
          acc[mo + mf][no + nf] = mfma16(a[mf][ks], b[nf][ks], acc[mo + mf][no + nf]);
  };

#define VM4()    asm volatile("s_waitcnt vmcnt(4)" ::: "memory")
  stageA(0, 0, 0); stageA(0, 0, 1);
  stageB(0, 0, 0); stageB(0, 0, 1);
  stageB(1, 1, 0); stageB(1, 1, 1);
  VM4();
  BAR();

  const int NT = NKT >> 1;
  for (int it = 0; it < NT; ++it) {
    int e = it << 1, o = e + 1;
    int e2 = (e + 2 >= NKT) ? 0 : e + 2;
    int o2 = (o + 2 >= NKT) ? 1 : o + 2;

    rdA(0, 0, af); rdB(0, 0, bf0);
    stageA(o, 1, 0);
    BAR(); LGKM0(); PRIO(1);
    MM(af, bf0, 0, 0);
    PRIO(0); BAR();

    rdB(0, 1, bf1);
    stageA(o, 1, 1);
    BAR(); LGKM0(); PRIO(1);
    MM(af, bf1, 0, 2);
    PRIO(0); BAR();

    rdA(0, 1, af);
    stageB(e2, 0, 0);
    BAR(); LGKM0(); PRIO(1);
    MM(af, bf1, 4, 2);
    PRIO(0); BAR();

    stageB(e2, 0, 1);
    BAR(); PRIO(1);
    MM(af, bf0, 4, 0);
    PRIO(0); VM4(); BAR();

    rdA(1, 0, af); rdB(1, 0, bf0);
    stageA(e2, 0, 0);
    BAR(); LGKM0(); PRIO(1);
    MM(af, bf0, 0, 0);
    PRIO(0); BAR();

    rdB(1, 1, bf1);
    stageA(e2, 0, 1);
    BAR(); LGKM0(); PRIO(1);
    MM(af, bf1, 0, 2);
    PRIO(0); BAR();

    rdA(1, 1, af);
    stageB(o2, 1, 0);
    BAR(); LGKM0(); PRIO(1);
    MM(af, bf1, 4, 2);
    PRIO(0); BAR();

    stageB(o2, 1, 1);
    BAR(); PRIO(1);
    MM(af, bf0, 4, 0);
    PRIO(0); VM4(); BAR();
  }
#undef VM4

#pragma unroll
  for (int mf = 0; mf < 8; ++mf)
#pragma unroll
    for (int nf = 0; nf < 4; ++nf)
#pragma unroll
      for (int r = 0; r < 4; ++r) {
        int row = m0 + (wm << 7) + (mf << 4) + (hi << 2) + r;
        int col = n0 + (wn << 6) + (nf << 4) + lo;
        if (OUT_BF16) ((u16*)Cout)[(size_t)row * N + col] = f2bf(acc[mf][nf][r]);
        else          ((float*)Cout)[(size_t)row * N + col] = acc[mf][nf][r];
      }
}

// ---------------- RoPE (in-place on bf16, optional output scale) ----------------
__global__ __launch_bounds__(256) void rope_kernel(u16* __restrict__ X,
                                                   const int* __restrict__ pos,
                                                   int ncols, int pitch, float scale) {
  int idx = blockIdx.x * 256 + threadIdx.x;
  int groups = ncols >> 3;
  int m = idx / groups;
  int gi = idx - m * groups;
  if (m >= MROWS) return;
  int head = gi >> 4;
  int d0 = (gi & 15) << 2;
  float p = (float)pos[m];
  u16* base = X + (size_t)m * pitch + head * 128;
  u16 xa[4], xb[4], oa[4], ob[4];
  *(uint2*)xa = *(const uint2*)(base + d0);
  *(uint2*)xb = *(const uint2*)(base + d0 + 64);
#pragma unroll
  for (int i = 0; i < 4; ++i) {
    float j = (float)(d0 + i);
    float inv = __expf(j * -0.14391156516030342f);  // ln(10000)/64
    float fr = p * inv;
    float s, c;
    sincosf(fr, &s, &c);
    float x1 = bf2f(xa[i]), x2 = bf2f(xb[i]);
    oa[i] = f2bf((x1 * c - x2 * s) * scale);
    ob[i] = f2bf((x2 * c + x1 * s) * scale);
  }
  *(uint2*)(base + d0) = *(uint2*)oa;
  *(uint2*)(base + d0 + 64) = *(uint2*)ob;
}

// ---------------- V transpose: QKV[m][5120 + g*128 + d] -> Vt[(b*8+g)*128 + d][s] ----------------
__global__ __launch_bounds__(256) void transpose_v(const u16* __restrict__ V,
                                                   u16* __restrict__ Vt) {
  int bid = blockIdx.x;
  int s0 = (bid & 31) << 6;
  int bg = bid >> 5;
  int b = bg >> 3, g = bg & 7;
  __shared__ u16 tile[64][128];
  int t = threadIdx.x;
#pragma unroll
  for (int r = 0; r < 4; ++r) {
    int c = (r << 8) + t;
    int row = c >> 4, cc = c & 15;
    *(uint4*)&tile[row][cc * 8] =
        *(const uint4*)(V + (size_t)(b * S_LEN + s0 + row) * QKV_N + g * 128 + cc * 8);
  }
  __syncthreads();
#pragma unroll
  for (int r = 0; r < 4; ++r) {
    int c = (r << 8) + t;
    int d = c >> 3, cs = c & 7;
    u16 tmp[8];
#pragma unroll
    for (int i = 0; i < 8; ++i) tmp[i] = tile[cs * 8 + i][d];
    *(uint4*)(Vt + ((size_t)bg * 128 + d) * S_LEN + s0 + cs * 8) = *(uint4*)tmp;
  }
}

// ---------------- Flash attention (causal, GQA 4:1), swapped-operand layout ----------------
__global__ __launch_bounds__(256) void attn_kernel(
    const u16* __restrict__ Q, const u16* __restrict__ K,
    const u16* __restrict__ Vt, u16* __restrict__ O) {
  int bid = blockIdx.x;
  int qt = 31 - (bid >> 6);          // heavy tiles first
  int bh = bid & 63;
  int b = bh >> 5, h = bh & 31;
  int g = h >> 2;
  __shared__ u16 Kl[64 * 128];
  __shared__ u16 Vl[128 * 64];
  __shared__ u16 Pl[4][16 * 72];     // per-wave P^T / O-bounce, pitch 72
  int t = threadIdx.x, w = t >> 6, lane = t & 63, lo = lane & 15, hi = lane >> 4;

  bf16x8 qf[4];   // B-operand: lane -> Q row (q=lo)
  {
    const u16* qb = Q + (size_t)(b * S_LEN + (qt << 6) + (w << 4) + lo) * QKV_N + h * 128;
#pragma unroll
    for (int kk = 0; kk < 4; ++kk) qf[kk] = *(const bf16x8*)(qb + kk * 32 + hi * 8);
  }
  const f32x4 fz = {0.f, 0.f, 0.f, 0.f};
  f32x4 acc[8];
#pragma unroll
  for (int f = 0; f < 8; ++f) acc[f] = fz;
  float mrun = -1e30f, lrun = 0.f;

  const u16* Kbase = K + (size_t)(b * S_LEN) * QKV_N + g * 128;
  const u16* Vbase = Vt + (size_t)((b << 3) + g) * 128 * S_LEN;

  int ntiles = qt + 1;
  for (int tile = 0; tile < ntiles; ++tile) {
    int s0 = tile << 6;
#pragma unroll
    for (int r = 0; r < 4; ++r) {              // stage K tile [64][128], chunk-swizzled
      int c = (r << 8) + (w << 6) + lane;
      int row = c >> 4, cc = c & 15;
      int src = cc ^ (row & 7);
      async16(Kbase + (size_t)(s0 + row) * QKV_N + src * 8,
              (char*)Kl + (r << 12) + (w << 10));
    }
#pragma unroll
    for (int r = 0; r < 4; ++r) {              // stage V^T tile [128][64], chunk-swizzled
      int c = (r << 8) + (w << 6) + lane;
      int row = c >> 3, cc = c & 7;
      int src = cc ^ (row & 7);
      async16(Vbase + (size_t)row * S_LEN + s0 + src * 8,
              (char*)Vl + (r << 12) + (w << 10));
    }
    __syncthreads();

    f32x4 sf[4];
#pragma unroll
    for (int j = 0; j < 4; ++j) {
      f32x4 sv = fz;
#pragma unroll
      for (int kk = 0; kk < 4; ++kk) {
        int row = (j << 4) + lo;
        int ch = ((kk << 2) + hi) ^ (row & 7);
        bf16x8 kf = *(const bf16x8*)(Kl + row * 128 + ch * 8);
        sv = __builtin_amdgcn_mfma_f32_16x16x32_bf16(kf, qf[kk], sv, 0, 0, 0);
      }
      sf[j] = sv;
    }
    if (tile == qt) {                           // causal mask on diagonal tile
      int q_rel = (w << 4) + lo;
#pragma unroll
      for (int j = 0; j < 4; ++j)
#pragma unroll
        for (int r = 0; r < 4; ++r)
          if (((j << 4) + (hi << 2) + r) > q_rel) sf[j][r] = -1e9f;
    }
    float pmax = sf[0][0];
#pragma unroll
    for (int j = 0; j < 4; ++j)
#pragma unroll
      for (int r = 0; r < 4; ++r) pmax = fmaxf(pmax, sf[j][r]);
    pmax = fmaxf(pmax, __shfl_xor(pmax, 16, 64));
    pmax = fmaxf(pmax, __shfl_xor(pmax, 32, 64));
    if (__any(pmax > mrun + 8.f)) {             // defer-max rescale (THR=8)
      float mn = fmaxf(mrun, pmax);
      float fsc = __expf(mrun - mn);
      mrun = mn;
      lrun *= fsc;
#pragma unroll
      for (int f = 0; f < 8; ++f)
#pragma unroll
        for (int r = 0; r < 4; ++r) acc[f][r] *= fsc;
    }
    float psum = 0.f;
#pragma unroll
    for (int j = 0; j < 4; ++j)
#pragma unroll
      for (int r = 0; r < 4; ++r) {
        float p = __expf(sf[j][r] - mrun);
        sf[j][r] = p;
        psum += p;
      }
    psum += __shfl_xor(psum, 16, 64);
    psum += __shfl_xor(psum, 32, 64);
    lrun += psum;

#pragma unroll
    for (int j = 0; j < 4; ++j) {
      uint2 pk;
      pk.x = cvtpk(sf[j][0], sf[j][1]);
      pk.y = cvtpk(sf[j][2], sf[j][3]);
      *(uint2*)&Pl[w][lo * 72 + (j << 4) + (hi << 2)] = pk;
    }
#pragma unroll
    for (int kk = 0; kk < 2; ++kk) {
      bf16x8 pf = *(const bf16x8*)&Pl[w][lo * 72 + (kk << 5) + (hi << 3)];
#pragma unroll
      for (int f = 0; f < 8; ++f) {
        int vrow = (f << 4) + lo;
        int phys = ((kk << 2) + hi) ^ (vrow & 7);
        bf16x8 vf = *(const bf16x8*)(Vl + vrow * 64 + phys * 8);
        acc[f] = __builtin_amdgcn_mfma_f32_16x16x32_bf16(vf, pf, acc[f], 0, 0, 0);
      }
    }
    __syncthreads();
  }

  float rl = 1.0f / lrun;
#pragma unroll
  for (int half = 0; half < 2; ++half) {
#pragma unroll
    for (int f2 = 0; f2 < 4; ++f2) {
      int f = (half << 2) + f2;
      uint2 pk;
      pk.x = cvtpk(acc[f][0] * rl, acc[f][1] * rl);
      pk.y = cvtpk(acc[f][2] * rl, acc[f][3] * rl);
      *(uint2*)&Pl[w][lo * 72 + (f2 << 4) + (hi << 2)] = pk;
    }
#pragma unroll
    for (int it = 0; it < 2; ++it) {
      int rowq = (lane >> 3) + (it << 3);
      int c8 = lane & 7;
      uint4 val = *(const uint4*)&Pl[w][rowq * 72 + c8 * 8];
      *(uint4*)(O + (size_t)(b * S_LEN + (qt << 6) + (w << 4) + rowq) * 4096 +
                h * 128 + (half << 6) + c8 * 8) = val;
    }
  }
}

// ---------------- launch ----------------
extern "C" void kernel_launch(void* const* d_in, const int* in_sizes, int n_in,
                              void* d_out, int out_size, void* d_ws, size_t ws_size,
                              hipStream_t stream) {
  const float* hidden = (const float*)d_in[0];
  const int* pos = (const int*)d_in[1];
  const float* Wq = (const float*)d_in[2];
  const float* Wk = (const float*)d_in[3];
  const float* Wv = (const float*)d_in[4];
  const float* Wo = (const float*)d_in[5];
  float* out = (float*)d_out;

  u16* hb   = (u16*)d_ws;                 // [4096][4096]
  u16* wqb  = hb   + 16777216;            // [4096][4096]  } contiguous -> fused
  u16* wkb  = wqb  + 16777216;            // [1024][4096]  }   B matrix [6144][4096]
  u16* wvb  = wkb  + 4194304;             // [1024][4096]  }
  u16* wob  = wvb  + 4194304;             // [4096][4096]
  u16* QKVb = wob  + 16777216;            // [4096][6144]
  u16* Vtb  = QKVb + 25165824;            // [16*128][2048]
  u16* Ob   = Vtb  + 4194304;             // [4096][4096]

  cvt_f32_bf16<<<8192, 256, 0, stream>>>(hidden, hb, 16777216);
  cvt_f32_bf16<<<8192, 256, 0, stream>>>(Wq, wqb, 16777216);
  cvt_f32_bf16<<<2048, 256, 0, stream>>>(Wk, wkb, 4194304);
  cvt_f32_bf16<<<2048, 256, 0, stream>>>(Wv, wvb, 4194304);
  cvt_f32_bf16<<<8192, 256, 0, stream>>>(Wo, wob, 16777216);

  // QKV: 4-fat-wave experiment; 16x24 tiles = 384 blocks (XC=4,SR=8,SC=6)
  gemm4w<<<384, 256, 0, stream>>>(hb, wqb, QKVb, 4096, QKV_N, 4096, 4, 8, 6);

  rope_kernel<<<8192, 256, 0, stream>>>(QKVb, pos, 4096, QKV_N, 0.08838834764831845f); // Q (pre-scaled)
  rope_kernel<<<2048, 256, 0, stream>>>(QKVb + 4096, pos, 1024, QKV_N, 1.0f);          // K

  transpose_v<<<512, 256, 0, stream>>>(QKVb + 5120, Vtb);

  attn_kernel<<<2048, 256, 0, stream>>>(QKVb, QKVb + 4096, Vtb, Ob);

  // O-proj: r11 kernel (control); 16x16 tiles = 256 blocks (XC=2,SR=4,SC=8)
  gemm256<0><<<256, 512, 0, stream>>>(Ob, wob, out, 4096, 4096, 4096, 2, 4, 8);
}

// Round 15
// 541.730 us; speedup vs baseline: 1.2367x; 1.2367x over previous
//
#include <hip/hip_runtime.h>

#define S_LEN 2048
#define BATCH 2
#define HID 4096
#define NH 32
#define NKV 8
#define DH 128
#define MROWS (BATCH*S_LEN)   // 4096
#define QKV_N 6144

typedef unsigned short u16;
typedef unsigned int u32;
typedef __bf16 bf16x8 __attribute__((ext_vector_type(8)));
typedef float f32x4 __attribute__((ext_vector_type(4)));
typedef u16 u16x8 __attribute__((ext_vector_type(8)));

__device__ __forceinline__ u16 f2bf(float f) {           // round-half-up (2 insts)
  union { float f; u32 u; } v; v.f = f;
  return (u16)((v.u + 0x8000u) >> 16);
}
__device__ __forceinline__ float bf2f(u16 h) {
  union { u32 u; float f; } v; v.u = ((u32)h) << 16;
  return v.f;
}
__device__ __forceinline__ u32 cvtpk(float a, float b) { // packs bf16(a)|bf16(b)<<16
  u32 r;
  asm("v_cvt_pk_bf16_f32 %0, %1, %2" : "=v"(r) : "v"(a), "v"(b));
  return r;
}
__device__ __forceinline__ void async16(const void* g, void* l) {
  __builtin_amdgcn_global_load_lds(
      (const __attribute__((address_space(1))) u32*)g,
      (__attribute__((address_space(3))) u32*)l, 16, 0, 0);
}
__device__ __forceinline__ f32x4 mfma16(bf16x8 a, bf16x8 b, f32x4 c) {
  return __builtin_amdgcn_mfma_f32_16x16x32_bf16(a, b, c, 0, 0, 0);
}

#define BAR()    __builtin_amdgcn_s_barrier()
#define LGKM0()  asm volatile("s_waitcnt lgkmcnt(0)" ::: "memory")
#define PRIO(x)  __builtin_amdgcn_s_setprio(x)

// ---------------- fp32 -> bf16 conversion ----------------
__global__ __launch_bounds__(256) void cvt_f32_bf16(const float* __restrict__ in,
                                                    u16* __restrict__ out, int n) {
  int i0 = (blockIdx.x * 256 + threadIdx.x) * 8;
  if (i0 >= n) return;
  float4 a = *(const float4*)(in + i0);
  float4 b = *(const float4*)(in + i0 + 4);
  u16x8 r;
  r[0]=f2bf(a.x); r[1]=f2bf(a.y); r[2]=f2bf(a.z); r[3]=f2bf(a.w);
  r[4]=f2bf(b.x); r[5]=f2bf(b.y); r[6]=f2bf(b.z); r[7]=f2bf(b.w);
  *(u16x8*)(out + i0) = r;
}

// ---------------- 256x256 NT bf16 GEMM (r11 version — session best) --------
// 8-phase in-phase-read schedule, parity dbuf, 3-bit chunk swizzle (0 confl),
// 2-D XCD map, counted vmcnt(4), setprio, 16x16x32 MFMA. Nine structural
// variants (r5-r14) bracket the same ~860 TF — this is the session's GEMM.
template<int OUT_BF16>
__global__ __launch_bounds__(512, 2) void gemm256(
    const u16* __restrict__ A, const u16* __restrict__ B, void* __restrict__ Cout,
    int M, int N, int K, int XC, int SR, int SC) {
  __shared__ u16 As[2][2][64 * 128];   // [parity-buf][128-row half][128x64]
  __shared__ u16 Bs[2][2][64 * 128];
  const int NKT = K >> 6;
  int bid = (int)blockIdx.x;
  int xcd = bid & 7, l = bid >> 3;
  int tm = (xcd / XC) * SR + l / SC;
  int tn = (xcd % XC) * SC + l % SC;
  int m0 = tm << 8, n0 = tn << 8;
  int t = threadIdx.x;
  int w = t >> 6, lane = t & 63, lo = lane & 15, hi = lane >> 4;
  int wm = w >> 2, wn = w & 3;
  int rbb = (wn & 1) << 6;

  int srow = (w << 3) + (lane >> 3);
  int scol = (lane & 7) << 3;

  auto stageA = [&](int kt, int buf, int h) {
#pragma unroll
    for (int c2 = 0; c2 < 2; ++c2) {
      int row = (c2 << 6) + srow;
      int col = scol ^ ((row & 7) << 3);
      async16(A + (size_t)(m0 + (h << 7) + row) * K + (kt << 6) + col,
              (char*)&As[buf][h][0] + (c2 << 13) + (w << 10));
    }
  };
  auto stageB = [&](int kt, int buf, int h) {
#pragma unroll
    for (int c2 = 0; c2 < 2; ++c2) {
      int row = (c2 << 6) + srow;
      int col = scol ^ ((row & 7) << 3);
      async16(B + (size_t)(n0 + (h << 7) + row) * K + (kt << 6) + col,
              (char*)&Bs[buf][h][0] + (c2 << 13) + (w << 10));
    }
  };

  const f32x4 fz = {0.f, 0.f, 0.f, 0.f};
  f32x4 acc[8][4];
#pragma unroll
  for (int i = 0; i < 8; ++i)
#pragma unroll
    for (int j = 0; j < 4; ++j) acc[i][j] = fz;
  bf16x8 af[4][2], bf0[2][2], bf1[2][2];

  auto rdA = [&](int c, int half, bf16x8 (&dst)[4][2]) {
    const u16* Ab = &As[c][wm][0];
#pragma unroll
    for (int mf = 0; mf < 4; ++mf)
#pragma unroll
      for (int ks = 0; ks < 2; ++ks) {
        int ra = (half << 6) + (mf << 4) + lo;
        dst[mf][ks] = *(const bf16x8*)(Ab + (ra << 6) +
                      (((ks << 5) + (hi << 3)) ^ ((ra & 7) << 3)));
      }
  };
  auto rdB = [&](int c, int bfrag, bf16x8 (&dst)[2][2]) {
    const u16* Bb = &Bs[c][wn >> 1][0];
#pragma unroll
    for (int nf = 0; nf < 2; ++nf)
#pragma unroll
      for (int ks = 0; ks < 2; ++ks) {
        int rb = rbb + (bfrag << 5) + (nf << 4) + lo;
        dst[nf][ks] = *(const bf16x8*)(Bb + (rb << 6) +
                      (((ks << 5) + (hi << 3)) ^ ((rb & 7) << 3)));
      }
  };
  auto MM = [&](bf16x8 (&a)[4][2], bf16x8 (&b)[2][2], int mo, int no) {
#pragma unroll
    for (int mf = 0; mf < 4; ++mf)
#pragma unroll
      for (int nf = 0; nf < 2; ++nf)
#pragma unroll
        for (int ks = 0; ks < 2; ++ks)
          acc[mo + mf][no + nf] = mfma16(a[mf][ks], b[nf][ks], acc[mo + mf][no + nf]);
  };

#define VM4()    asm volatile("s_waitcnt vmcnt(4)" ::: "memory")
  stageA(0, 0, 0); stageA(0, 0, 1);
  stageB(0, 0, 0); stageB(0, 0, 1);
  stageB(1, 1, 0); stageB(1, 1, 1);
  VM4();
  BAR();

  const int NT = NKT >> 1;
  for (int it = 0; it < NT; ++it) {
    int e = it << 1, o = e + 1;
    int e2 = (e + 2 >= NKT) ? 0 : e + 2;
    int o2 = (o + 2 >= NKT) ? 1 : o + 2;

    rdA(0, 0, af); rdB(0, 0, bf0);
    stageA(o, 1, 0);
    BAR(); LGKM0(); PRIO(1);
    MM(af, bf0, 0, 0);
    PRIO(0); BAR();

    rdB(0, 1, bf1);
    stageA(o, 1, 1);
    BAR(); LGKM0(); PRIO(1);
    MM(af, bf1, 0, 2);
    PRIO(0); BAR();

    rdA(0, 1, af);
    stageB(e2, 0, 0);
    BAR(); LGKM0(); PRIO(1);
    MM(af, bf1, 4, 2);
    PRIO(0); BAR();

    stageB(e2, 0, 1);
    BAR(); PRIO(1);
    MM(af, bf0, 4, 0);
    PRIO(0); VM4(); BAR();

    rdA(1, 0, af); rdB(1, 0, bf0);
    stageA(e2, 0, 0);
    BAR(); LGKM0(); PRIO(1);
    MM(af, bf0, 0, 0);
    PRIO(0); BAR();

    rdB(1, 1, bf1);
    stageA(e2, 0, 1);
    BAR(); LGKM0(); PRIO(1);
    MM(af, bf1, 0, 2);
    PRIO(0); BAR();

    rdA(1, 1, af);
    stageB(o2, 1, 0);
    BAR(); LGKM0(); PRIO(1);
    MM(af, bf1, 4, 2);
    PRIO(0); BAR();

    stageB(o2, 1, 1);
    BAR(); PRIO(1);
    MM(af, bf0, 4, 0);
    PRIO(0); VM4(); BAR();
  }
#undef VM4

#pragma unroll
  for (int mf = 0; mf < 8; ++mf)
#pragma unroll
    for (int nf = 0; nf < 4; ++nf)
#pragma unroll
      for (int r = 0; r < 4; ++r) {
        int row = m0 + (wm << 7) + (mf << 4) + (hi << 2) + r;
        int col = n0 + (wn << 6) + (nf << 4) + lo;
        if (OUT_BF16) ((u16*)Cout)[(size_t)row * N + col] = f2bf(acc[mf][nf][r]);
        else          ((float*)Cout)[(size_t)row * N + col] = acc[mf][nf][r];
      }
}

// ---------------- RoPE (in-place on bf16, optional output scale) ----------------
__global__ __launch_bounds__(256) void rope_kernel(u16* __restrict__ X,
                                                   const int* __restrict__ pos,
                                                   int ncols, int pitch, float scale) {
  int idx = blockIdx.x * 256 + threadIdx.x;
  int groups = ncols >> 3;
  int m = idx / groups;
  int gi = idx - m * groups;
  if (m >= MROWS) return;
  int head = gi >> 4;
  int d0 = (gi & 15) << 2;
  float p = (float)pos[m];
  u16* base = X + (size_t)m * pitch + head * 128;
  u16 xa[4], xb[4], oa[4], ob[4];
  *(uint2*)xa = *(const uint2*)(base + d0);
  *(uint2*)xb = *(const uint2*)(base + d0 + 64);
#pragma unroll
  for (int i = 0; i < 4; ++i) {
    float j = (float)(d0 + i);
    float inv = __expf(j * -0.14391156516030342f);  // ln(10000)/64
    float fr = p * inv;
    float s, c;
    sincosf(fr, &s, &c);
    float x1 = bf2f(xa[i]), x2 = bf2f(xb[i]);
    oa[i] = f2bf((x1 * c - x2 * s) * scale);
    ob[i] = f2bf((x2 * c + x1 * s) * scale);
  }
  *(uint2*)(base + d0) = *(uint2*)oa;
  *(uint2*)(base + d0 + 64) = *(uint2*)ob;
}

// ---------------- V transpose: QKV[m][5120 + g*128 + d] -> Vt[(b*8+g)*128 + d][s] ----------------
__global__ __launch_bounds__(256) void transpose_v(const u16* __restrict__ V,
                                                   u16* __restrict__ Vt) {
  int bid = blockIdx.x;
  int s0 = (bid & 31) << 6;
  int bg = bid >> 5;
  int b = bg >> 3, g = bg & 7;
  __shared__ u16 tile[64][128];
  int t = threadIdx.x;
#pragma unroll
  for (int r = 0; r < 4; ++r) {
    int c = (r << 8) + t;
    int row = c >> 4, cc = c & 15;
    *(uint4*)&tile[row][cc * 8] =
        *(const uint4*)(V + (size_t)(b * S_LEN + s0 + row) * QKV_N + g * 128 + cc * 8);
  }
  __syncthreads();
#pragma unroll
  for (int r = 0; r < 4; ++r) {
    int c = (r << 8) + t;
    int d = c >> 3, cs = c & 7;
    u16 tmp[8];
#pragma unroll
    for (int i = 0; i < 8; ++i) tmp[i] = tile[cs * 8 + i][d];
    *(uint4*)(Vt + ((size_t)bg * 128 + d) * S_LEN + s0 + cs * 8) = *(uint4*)tmp;
  }
}

// ---------------- Flash attention, r15: double-buffered K/V stage-ahead ----
// block = (b, h, 64-row q-tile, heavy-first); 4 waves x 16 q-rows; KV tile 64.
// r15 change: Kl/Vl double-buffered (73KB LDS -> 2 blocks/CU). Per tile:
// stage(t+1 -> buf c^1) issued BEFORE compute on buf c; ONE __syncthreads()
// per tile at the end (its implicit vmcnt(0)+lgkmcnt(0) drains the stage
// issued ~a full compute-phase earlier -> near-zero stall). Ledger: buf c^1
// was last read in iter t-1 and all waves passed t-1's end barrier before
// iter t's stage -> no WAR race; end barrier of t guarantees t+1's K/V
// landed for all waves before iter t+1 reads them.
__global__ __launch_bounds__(256) void attn_kernel(
    const u16* __restrict__ Q, const u16* __restrict__ K,
    const u16* __restrict__ Vt, u16* __restrict__ O) {
  int bid = blockIdx.x;
  int qt = 31 - (bid >> 6);          // heavy tiles first
  int bh = bid & 63;
  int b = bh >> 5, h = bh & 31;
  int g = h >> 2;
  __shared__ u16 Kl[2][64 * 128];
  __shared__ u16 Vl[2][128 * 64];
  __shared__ u16 Pl[4][16 * 72];     // per-wave P^T / O-bounce, pitch 72
  int t = threadIdx.x, w = t >> 6, lane = t & 63, lo = lane & 15, hi = lane >> 4;

  bf16x8 qf[4];   // B-operand: lane -> Q row (q=lo)
  {
    const u16* qb = Q + (size_t)(b * S_LEN + (qt << 6) + (w << 4) + lo) * QKV_N + h * 128;
#pragma unroll
    for (int kk = 0; kk < 4; ++kk) qf[kk] = *(const bf16x8*)(qb + kk * 32 + hi * 8);
  }
  const f32x4 fz = {0.f, 0.f, 0.f, 0.f};
  f32x4 acc[8];
#pragma unroll
  for (int f = 0; f < 8; ++f) acc[f] = fz;
  float mrun = -1e30f, lrun = 0.f;

  const u16* Kbase = K + (size_t)(b * S_LEN) * QKV_N + g * 128;
  const u16* Vbase = Vt + (size_t)((b << 3) + g) * 128 * S_LEN;

  auto stageKV = [&](int tile, int buf) {
    int s0 = tile << 6;
#pragma unroll
    for (int r = 0; r < 4; ++r) {              // K tile [64][128], chunk-swizzled
      int c = (r << 8) + (w << 6) + lane;
      int row = c >> 4, cc = c & 15;
      int src = cc ^ (row & 7);
      async16(Kbase + (size_t)(s0 + row) * QKV_N + src * 8,
              (char*)&Kl[buf][0] + (r << 12) + (w << 10));
    }
#pragma unroll
    for (int r = 0; r < 4; ++r) {              // V^T tile [128][64], chunk-swizzled
      int c = (r << 8) + (w << 6) + lane;
      int row = c >> 3, cc = c & 7;
      int src = cc ^ (row & 7);
      async16(Vbase + (size_t)row * S_LEN + s0 + src * 8,
              (char*)&Vl[buf][0] + (r << 12) + (w << 10));
    }
  };

  int ntiles = qt + 1;
  stageKV(0, 0);
  __syncthreads();                              // drains prologue stage

  for (int tile = 0; tile < ntiles; ++tile) {
    int c = tile & 1;
    if (tile + 1 < ntiles) stageKV(tile + 1, c ^ 1);   // overlaps compute below

    f32x4 sf[4];
#pragma unroll
    for (int j = 0; j < 4; ++j) {
      f32x4 sv = fz;
#pragma unroll
      for (int kk = 0; kk < 4; ++kk) {
        int row = (j << 4) + lo;
        int ch = ((kk << 2) + hi) ^ (row & 7);
        bf16x8 kf = *(const bf16x8*)(&Kl[c][0] + row * 128 + ch * 8);
        sv = __builtin_amdgcn_mfma_f32_16x16x32_bf16(kf, qf[kk], sv, 0, 0, 0);
      }
      sf[j] = sv;
    }
    if (tile == qt) {                           // causal mask on diagonal tile
      int q_rel = (w << 4) + lo;
#pragma unroll
      for (int j = 0; j < 4; ++j)
#pragma unroll
        for (int r = 0; r < 4; ++r)
          if (((j << 4) + (hi << 2) + r) > q_rel) sf[j][r] = -1e9f;
    }
    float pmax = sf[0][0];
#pragma unroll
    for (int j = 0; j < 4; ++j)
#pragma unroll
      for (int r = 0; r < 4; ++r) pmax = fmaxf(pmax, sf[j][r]);
    pmax = fmaxf(pmax, __shfl_xor(pmax, 16, 64));
    pmax = fmaxf(pmax, __shfl_xor(pmax, 32, 64));
    if (__any(pmax > mrun + 8.f)) {             // defer-max rescale (THR=8)
      float mn = fmaxf(mrun, pmax);
      float fsc = __expf(mrun - mn);
      mrun = mn;
      lrun *= fsc;
#pragma unroll
      for (int f = 0; f < 8; ++f)
#pragma unroll
        for (int r = 0; r < 4; ++r) acc[f][r] *= fsc;
    }
    float psum = 0.f;
#pragma unroll
    for (int j = 0; j < 4; ++j)
#pragma unroll
      for (int r = 0; r < 4; ++r) {
        float p = __expf(sf[j][r] - mrun);
        sf[j][r] = p;
        psum += p;
      }
    psum += __shfl_xor(psum, 16, 64);
    psum += __shfl_xor(psum, 32, 64);
    lrun += psum;

#pragma unroll
    for (int j = 0; j < 4; ++j) {
      uint2 pk;
      pk.x = cvtpk(sf[j][0], sf[j][1]);
      pk.y = cvtpk(sf[j][2], sf[j][3]);
      *(uint2*)&Pl[w][lo * 72 + (j << 4) + (hi << 2)] = pk;
    }
#pragma unroll
    for (int kk = 0; kk < 2; ++kk) {
      bf16x8 pf = *(const bf16x8*)&Pl[w][lo * 72 + (kk << 5) + (hi << 3)];
#pragma unroll
      for (int f = 0; f < 8; ++f) {
        int vrow = (f << 4) + lo;
        int phys = ((kk << 2) + hi) ^ (vrow & 7);
        bf16x8 vf = *(const bf16x8*)(&Vl[c][0] + vrow * 64 + phys * 8);
        acc[f] = __builtin_amdgcn_mfma_f32_16x16x32_bf16(vf, pf, acc[f], 0, 0, 0);
      }
    }
    __syncthreads();   // one barrier/tile: drains stage(t+1); closes buf reuse
  }

  float rl = 1.0f / lrun;
#pragma unroll
  for (int half = 0; half < 2; ++half) {
#pragma unroll
    for (int f2 = 0; f2 < 4; ++f2) {
      int f = (half << 2) + f2;
      uint2 pk;
      pk.x = cvtpk(acc[f][0] * rl, acc[f][1] * rl);
      pk.y = cvtpk(acc[f][2] * rl, acc[f][3] * rl);
      *(uint2*)&Pl[w][lo * 72 + (f2 << 4) + (hi << 2)] = pk;
    }
#pragma unroll
    for (int it = 0; it < 2; ++it) {
      int rowq = (lane >> 3) + (it << 3);
      int c8 = lane & 7;
      uint4 val = *(const uint4*)&Pl[w][rowq * 72 + c8 * 8];
      *(uint4*)(O + (size_t)(b * S_LEN + (qt << 6) + (w << 4) + rowq) * 4096 +
                h * 128 + (half << 6) + c8 * 8) = val;
    }
  }
}

// ---------------- launch ----------------
extern "C" void kernel_launch(void* const* d_in, const int* in_sizes, int n_in,
                              void* d_out, int out_size, void* d_ws, size_t ws_size,
                              hipStream_t stream) {
  const float* hidden = (const float*)d_in[0];
  const int* pos = (const int*)d_in[1];
  const float* Wq = (const float*)d_in[2];
  const float* Wk = (const float*)d_in[3];
  const float* Wv = (const float*)d_in[4];
  const float* Wo = (const float*)d_in[5];
  float* out = (float*)d_out;

  u16* hb   = (u16*)d_ws;                 // [4096][4096]
  u16* wqb  = hb   + 16777216;            // [4096][4096]  } contiguous -> fused
  u16* wkb  = wqb  + 16777216;            // [1024][4096]  }   B matrix [6144][4096]
  u16* wvb  = wkb  + 4194304;             // [1024][4096]  }
  u16* wob  = wvb  + 4194304;             // [4096][4096]
  u16* QKVb = wob  + 16777216;            // [4096][6144]
  u16* Vtb  = QKVb + 25165824;            // [16*128][2048]
  u16* Ob   = Vtb  + 4194304;             // [4096][4096]

  cvt_f32_bf16<<<8192, 256, 0, stream>>>(hidden, hb, 16777216);
  cvt_f32_bf16<<<8192, 256, 0, stream>>>(Wq, wqb, 16777216);
  cvt_f32_bf16<<<2048, 256, 0, stream>>>(Wk, wkb, 4194304);
  cvt_f32_bf16<<<2048, 256, 0, stream>>>(Wv, wvb, 4194304);
  cvt_f32_bf16<<<8192, 256, 0, stream>>>(Wo, wob, 16777216);

  // QKV: r11 gemm256 (session best); 16x24 tiles = 384 blocks (XC=4,SR=8,SC=6)
  gemm256<1><<<384, 512, 0, stream>>>(hb, wqb, QKVb, 4096, QKV_N, 4096, 4, 8, 6);

  rope_kernel<<<8192, 256, 0, stream>>>(QKVb, pos, 4096, QKV_N, 0.08838834764831845f); // Q (pre-scaled)
  rope_kernel<<<2048, 256, 0, stream>>>(QKVb + 4096, pos, 1024, QKV_N, 1.0f);          // K

  transpose_v<<<512, 256, 0, stream>>>(QKVb + 5120, Vtb);

  attn_kernel<<<2048, 256, 0, stream>>>(QKVb, QKVb + 4096, Vtb, Ob);

  // O-proj: r11 kernel; 16x16 tiles = 256 blocks (XC=2,SR=4,SC=8)
  gemm256<0><<<256, 512, 0, stream>>>(Ob, wob, out, 4096, 4096, 4096, 2, 4, 8);
}

// Round 16
// 516.245 us; speedup vs baseline: 1.2977x; 1.0494x over previous
//
#include <hip/hip_runtime.h>

#define S_LEN 2048
#define BATCH 2
#define HID 4096
#define NH 32
#define NKV 8
#define DH 128
#define MROWS (BATCH*S_LEN)   // 4096
#define QKV_N 6144

typedef unsigned short u16;
typedef unsigned int u32;
typedef __bf16 bf16x8 __attribute__((ext_vector_type(8)));
typedef float f32x4 __attribute__((ext_vector_type(4)));
typedef u16 u16x8 __attribute__((ext_vector_type(8)));

__device__ __forceinline__ u16 f2bf(float f) {           // round-half-up (2 insts)
  union { float f; u32 u; } v; v.f = f;
  return (u16)((v.u + 0x8000u) >> 16);
}
__device__ __forceinline__ float bf2f(u16 h) {
  union { u32 u; float f; } v; v.u = ((u32)h) << 16;
  return v.f;
}
__device__ __forceinline__ u32 cvtpk(float a, float b) { // packs bf16(a)|bf16(b)<<16
  u32 r;
  asm("v_cvt_pk_bf16_f32 %0, %1, %2" : "=v"(r) : "v"(a), "v"(b));
  return r;
}
__device__ __forceinline__ void async16(const void* g, void* l) {
  __builtin_amdgcn_global_load_lds(
      (const __attribute__((address_space(1))) u32*)g,
      (__attribute__((address_space(3))) u32*)l, 16, 0, 0);
}
__device__ __forceinline__ f32x4 mfma16(bf16x8 a, bf16x8 b, f32x4 c) {
  return __builtin_amdgcn_mfma_f32_16x16x32_bf16(a, b, c, 0, 0, 0);
}

#define BAR()    __builtin_amdgcn_s_barrier()
#define LGKM0()  asm volatile("s_waitcnt lgkmcnt(0)" ::: "memory")
#define PRIO(x)  __builtin_amdgcn_s_setprio(x)

// ---------------- fp32 -> bf16 conversion ----------------
__global__ __launch_bounds__(256) void cvt_f32_bf16(const float* __restrict__ in,
                                                    u16* __restrict__ out, int n) {
  int i0 = (blockIdx.x * 256 + threadIdx.x) * 8;
  if (i0 >= n) return;
  float4 a = *(const float4*)(in + i0);
  float4 b = *(const float4*)(in + i0 + 4);
  u16x8 r;
  r[0]=f2bf(a.x); r[1]=f2bf(a.y); r[2]=f2bf(a.z); r[3]=f2bf(a.w);
  r[4]=f2bf(b.x); r[5]=f2bf(b.y); r[6]=f2bf(b.z); r[7]=f2bf(b.w);
  *(u16x8*)(out + i0) = r;
}

// ---------------- 256x256 NT bf16 GEMM (r11 core; r16: MODE + split-K) -----
// Core schedule unchanged (8-phase in-phase reads, parity dbuf, 3-bit chunk
// swizzle = 0 conflicts, counted vmcnt(4), setprio) — nine variants bracket
// ~860 TF; this is the session GEMM. r16 adds makespan surgery:
//  MODE 0: fp32 full C, 2-D XCD map (O-proj, 256 blocks = 1.0 rounds)
//  MODE 1: bf16 full C, LINEAR tile map tileBase+bid (QKV round 1, 256 blocks)
//  MODE 2: split-K partial: bid = half*128+slot, tile = tileBase+slot,
//          kOff = half*kSpan, fp32 [256][256] slab -> (half? p1 : p0)+slot*64K
// (QKV was 384 tiles @1 blk/CU = 2.0 serial rounds, 25% idle; now 1.0-round
// full-K pass + 1.0-round half-K pass + small reduce. Linear map's XCD
// locality loss is free: r9 showed time is fetch-invariant.)
template<int MODE>
__global__ __launch_bounds__(512, 2) void gemm256(
    const u16* __restrict__ A, const u16* __restrict__ B, void* __restrict__ Cout,
    int M, int N, int K, int XC, int SR, int SC,
    int kSpan, int nkt, int tileBase, float* p0, float* p1) {
  __shared__ u16 As[2][2][64 * 128];   // [parity-buf][128-row half][128x64]
  __shared__ u16 Bs[2][2][64 * 128];
  const int NKT = nkt;
  int bid = (int)blockIdx.x;
  int tm, tn, half = 0, slot = 0;
  if (MODE == 0) {
    int xcd = bid & 7, l = bid >> 3;
    tm = (xcd / XC) * SR + l / SC;
    tn = (xcd % XC) * SC + l % SC;
  } else {
    int nTN = N >> 8;
    int lin;
    if (MODE == 2) { half = bid >> 7; slot = bid & 127; lin = tileBase + slot; }
    else           { lin = tileBase + bid; }
    tm = lin / nTN; tn = lin - tm * nTN;
  }
  const int koff = (MODE == 2) ? half * kSpan : 0;
  int m0 = tm << 8, n0 = tn << 8;
  int t = threadIdx.x;
  int w = t >> 6, lane = t & 63, lo = lane & 15, hi = lane >> 4;
  int wm = w >> 2, wn = w & 3;
  int rbb = (wn & 1) << 6;

  int srow = (w << 3) + (lane >> 3);
  int scol = (lane & 7) << 3;

  auto stageA = [&](int kt, int buf, int h) {
#pragma unroll
    for (int c2 = 0; c2 < 2; ++c2) {
      int row = (c2 << 6) + srow;
      int col = scol ^ ((row & 7) << 3);
      async16(A + (size_t)(m0 + (h << 7) + row) * K + (kt << 6) + koff + col,
              (char*)&As[buf][h][0] + (c2 << 13) + (w << 10));
    }
  };
  auto stageB = [&](int kt, int buf, int h) {
#pragma unroll
    for (int c2 = 0; c2 < 2; ++c2) {
      int row = (c2 << 6) + srow;
      int col = scol ^ ((row & 7) << 3);
      async16(B + (size_t)(n0 + (h << 7) + row) * K + (kt << 6) + koff + col,
              (char*)&Bs[buf][h][0] + (c2 << 13) + (w << 10));
    }
  };

  const f32x4 fz = {0.f, 0.f, 0.f, 0.f};
  f32x4 acc[8][4];
#pragma unroll
  for (int i = 0; i < 8; ++i)
#pragma unroll
    for (int j = 0; j < 4; ++j) acc[i][j] = fz;
  bf16x8 af[4][2], bf0[2][2], bf1[2][2];

  auto rdA = [&](int c, int halfT, bf16x8 (&dst)[4][2]) {
    const u16* Ab = &As[c][wm][0];
#pragma unroll
    for (int mf = 0; mf < 4; ++mf)
#pragma unroll
      for (int ks = 0; ks < 2; ++ks) {
        int ra = (halfT << 6) + (mf << 4) + lo;
        dst[mf][ks] = *(const bf16x8*)(Ab + (ra << 6) +
                      (((ks << 5) + (hi << 3)) ^ ((ra & 7) << 3)));
      }
  };
  auto rdB = [&](int c, int bfrag, bf16x8 (&dst)[2][2]) {
    const u16* Bb = &Bs[c][wn >> 1][0];
#pragma unroll
    for (int nf = 0; nf < 2; ++nf)
#pragma unroll
      for (int ks = 0; ks < 2; ++ks) {
        int rb = rbb + (bfrag << 5) + (nf << 4) + lo;
        dst[nf][ks] = *(const bf16x8*)(Bb + (rb << 6) +
                      (((ks << 5) + (hi << 3)) ^ ((rb & 7) << 3)));
      }
  };
  auto MM = [&](bf16x8 (&a)[4][2], bf16x8 (&b)[2][2], int mo, int no) {
#pragma unroll
    for (int mf = 0; mf < 4; ++mf)
#pragma unroll
      for (int nf = 0; nf < 2; ++nf)
#pragma unroll
        for (int ks = 0; ks < 2; ++ks)
          acc[mo + mf][no + nf] = mfma16(a[mf][ks], b[nf][ks], acc[mo + mf][no + nf]);
  };

#define VM4()    asm volatile("s_waitcnt vmcnt(4)" ::: "memory")
  stageA(0, 0, 0); stageA(0, 0, 1);
  stageB(0, 0, 0); stageB(0, 0, 1);
  stageB(1, 1, 0); stageB(1, 1, 1);
  VM4();
  BAR();

  const int NT = NKT >> 1;
  for (int it = 0; it < NT; ++it) {
    int e = it << 1, o = e + 1;
    int e2 = (e + 2 >= NKT) ? 0 : e + 2;
    int o2 = (o + 2 >= NKT) ? 1 : o + 2;

    rdA(0, 0, af); rdB(0, 0, bf0);
    stageA(o, 1, 0);
    BAR(); LGKM0(); PRIO(1);
    MM(af, bf0, 0, 0);
    PRIO(0); BAR();

    rdB(0, 1, bf1);
    stageA(o, 1, 1);
    BAR(); LGKM0(); PRIO(1);
    MM(af, bf1, 0, 2);
    PRIO(0); BAR();

    rdA(0, 1, af);
    stageB(e2, 0, 0);
    BAR(); LGKM0(); PRIO(1);
    MM(af, bf1, 4, 2);
    PRIO(0); BAR();

    stageB(e2, 0, 1);
    BAR(); PRIO(1);
    MM(af, bf0, 4, 0);
    PRIO(0); VM4(); BAR();

    rdA(1, 0, af); rdB(1, 0, bf0);
    stageA(e2, 0, 0);
    BAR(); LGKM0(); PRIO(1);
    MM(af, bf0, 0, 0);
    PRIO(0); BAR();

    rdB(1, 1, bf1);
    stageA(e2, 0, 1);
    BAR(); LGKM0(); PRIO(1);
    MM(af, bf1, 0, 2);
    PRIO(0); BAR();

    rdA(1, 1, af);
    stageB(o2, 1, 0);
    BAR(); LGKM0(); PRIO(1);
    MM(af, bf1, 4, 2);
    PRIO(0); BAR();

    stageB(o2, 1, 1);
    BAR(); PRIO(1);
    MM(af, bf0, 4, 0);
    PRIO(0); VM4(); BAR();
  }
#undef VM4

  float* dst = (MODE == 2) ? ((half ? p1 : p0) + (size_t)slot * 65536) : nullptr;
#pragma unroll
  for (int mf = 0; mf < 8; ++mf)
#pragma unroll
    for (int nf = 0; nf < 4; ++nf)
#pragma unroll
      for (int r = 0; r < 4; ++r) {
        int r_l = (wm << 7) + (mf << 4) + (hi << 2) + r;
        int c_l = (wn << 6) + (nf << 4) + lo;
        if (MODE == 2) {
          dst[(size_t)r_l * 256 + c_l] = acc[mf][nf][r];
        } else {
          int row = m0 + r_l, col = n0 + c_l;
          if (MODE == 1) ((u16*)Cout)[(size_t)row * N + col] = f2bf(acc[mf][nf][r]);
          else           ((float*)Cout)[(size_t)row * N + col] = acc[mf][nf][r];
        }
      }
}

// ---------------- split-K reduce: QKVb[tile 256+s] = bf16(p0[s] + p1[s]) ----
__global__ __launch_bounds__(256) void reduce_splitk(const float* __restrict__ p0,
                                                     const float* __restrict__ p1,
                                                     u16* __restrict__ C) {
  int g = blockIdx.x * 256 + threadIdx.x;       // 1,048,576 threads x 8 elems
  int s = g >> 13;                              // tile slot 0-127
  int loc = g & 8191;
  int r_l = loc >> 5, c8 = loc & 31;
  int lin = 256 + s;
  int tm = lin / 24, tn = lin - tm * 24;
  size_t off = (size_t)s * 65536 + r_l * 256 + c8 * 8;
  float4 x0 = *(const float4*)(p0 + off);
  float4 x1 = *(const float4*)(p0 + off + 4);
  float4 y0 = *(const float4*)(p1 + off);
  float4 y1 = *(const float4*)(p1 + off + 4);
  u16x8 r;
  r[0]=f2bf(x0.x+y0.x); r[1]=f2bf(x0.y+y0.y); r[2]=f2bf(x0.z+y0.z); r[3]=f2bf(x0.w+y0.w);
  r[4]=f2bf(x1.x+y1.x); r[5]=f2bf(x1.y+y1.y); r[6]=f2bf(x1.z+y1.z); r[7]=f2bf(x1.w+y1.w);
  *(u16x8*)(C + (size_t)(tm * 256 + r_l) * QKV_N + tn * 256 + c8 * 8) = r;
}

// ---------------- RoPE (in-place on bf16, optional output scale) ----------------
__global__ __launch_bounds__(256) void rope_kernel(u16* __restrict__ X,
                                                   const int* __restrict__ pos,
                                                   int ncols, int pitch, float scale) {
  int idx = blockIdx.x * 256 + threadIdx.x;
  int groups = ncols >> 3;
  int m = idx / groups;
  int gi = idx - m * groups;
  if (m >= MROWS) return;
  int head = gi >> 4;
  int d0 = (gi & 15) << 2;
  float p = (float)pos[m];
  u16* base = X + (size_t)m * pitch + head * 128;
  u16 xa[4], xb[4], oa[4], ob[4];
  *(uint2*)xa = *(const uint2*)(base + d0);
  *(uint2*)xb = *(const uint2*)(base + d0 + 64);
#pragma unroll
  for (int i = 0; i < 4; ++i) {
    float j = (float)(d0 + i);
    float inv = __expf(j * -0.14391156516030342f);  // ln(10000)/64
    float fr = p * inv;
    float s, c;
    sincosf(fr, &s, &c);
    float x1 = bf2f(xa[i]), x2 = bf2f(xb[i]);
    oa[i] = f2bf((x1 * c - x2 * s) * scale);
    ob[i] = f2bf((x2 * c + x1 * s) * scale);
  }
  *(uint2*)(base + d0) = *(uint2*)oa;
  *(uint2*)(base + d0 + 64) = *(uint2*)ob;
}

// ---------------- V transpose: QKV[m][5120 + g*128 + d] -> Vt[(b*8+g)*128 + d][s] ----------------
__global__ __launch_bounds__(256) void transpose_v(const u16* __restrict__ V,
                                                   u16* __restrict__ Vt) {
  int bid = blockIdx.x;
  int s0 = (bid & 31) << 6;
  int bg = bid >> 5;
  int b = bg >> 3, g = bg & 7;
  __shared__ u16 tile[64][128];
  int t = threadIdx.x;
#pragma unroll
  for (int r = 0; r < 4; ++r) {
    int c = (r << 8) + t;
    int row = c >> 4, cc = c & 15;
    *(uint4*)&tile[row][cc * 8] =
        *(const uint4*)(V + (size_t)(b * S_LEN + s0 + row) * QKV_N + g * 128 + cc * 8);
  }
  __syncthreads();
#pragma unroll
  for (int r = 0; r < 4; ++r) {
    int c = (r << 8) + t;
    int d = c >> 3, cs = c & 7;
    u16 tmp[8];
#pragma unroll
    for (int i = 0; i < 8; ++i) tmp[i] = tile[cs * 8 + i][d];
    *(uint4*)(Vt + ((size_t)bg * 128 + d) * S_LEN + s0 + cs * 8) = *(uint4*)tmp;
  }
}

// ---------------- Flash attention (r15: double-buffered K/V stage-ahead) ----
__global__ __launch_bounds__(256) void attn_kernel(
    const u16* __restrict__ Q, const u16* __restrict__ K,
    const u16* __restrict__ Vt, u16* __restrict__ O) {
  int bid = blockIdx.x;
  int qt = 31 - (bid >> 6);          // heavy tiles first
  int bh = bid & 63;
  int b = bh >> 5, h = bh & 31;
  int g = h >> 2;
  __shared__ u16 Kl[2][64 * 128];
  __shared__ u16 Vl[2][128 * 64];
  __shared__ u16 Pl[4][16 * 72];     // per-wave P^T / O-bounce, pitch 72
  int t = threadIdx.x, w = t >> 6, lane = t & 63, lo = lane & 15, hi = lane >> 4;

  bf16x8 qf[4];   // B-operand: lane -> Q row (q=lo)
  {
    const u16* qb = Q + (size_t)(b * S_LEN + (qt << 6) + (w << 4) + lo) * QKV_N + h * 128;
#pragma unroll
    for (int kk = 0; kk < 4; ++kk) qf[kk] = *(const bf16x8*)(qb + kk * 32 + hi * 8);
  }
  const f32x4 fz = {0.f, 0.f, 0.f, 0.f};
  f32x4 acc[8];
#pragma unroll
  for (int f = 0; f < 8; ++f) acc[f] = fz;
  float mrun = -1e30f, lrun = 0.f;

  const u16* Kbase = K + (size_t)(b * S_LEN) * QKV_N + g * 128;
  const u16* Vbase = Vt + (size_t)((b << 3) + g) * 128 * S_LEN;

  auto stageKV = [&](int tile, int buf) {
    int s0 = tile << 6;
#pragma unroll
    for (int r = 0; r < 4; ++r) {              // K tile [64][128], chunk-swizzled
      int c = (r << 8) + (w << 6) + lane;
      int row = c >> 4, cc = c & 15;
      int src = cc ^ (row & 7);
      async16(Kbase + (size_t)(s0 + row) * QKV_N + src * 8,
              (char*)&Kl[buf][0] + (r << 12) + (w << 10));
    }
#pragma unroll
    for (int r = 0; r < 4; ++r) {              // V^T tile [128][64], chunk-swizzled
      int c = (r << 8) + (w << 6) + lane;
      int row = c >> 3, cc = c & 7;
      int src = cc ^ (row & 7);
      async16(Vbase + (size_t)row * S_LEN + s0 + src * 8,
              (char*)&Vl[buf][0] + (r << 12) + (w << 10));
    }
  };

  int ntiles = qt + 1;
  stageKV(0, 0);
  __syncthreads();

  for (int tile = 0; tile < ntiles; ++tile) {
    int c = tile & 1;
    if (tile + 1 < ntiles) stageKV(tile + 1, c ^ 1);   // overlaps compute below

    f32x4 sf[4];
#pragma unroll
    for (int j = 0; j < 4; ++j) {
      f32x4 sv = fz;
#pragma unroll
      for (int kk = 0; kk < 4; ++kk) {
        int row = (j << 4) + lo;
        int ch = ((kk << 2) + hi) ^ (row & 7);
        bf16x8 kf = *(const bf16x8*)(&Kl[c][0] + row * 128 + ch * 8);
        sv = __builtin_amdgcn_mfma_f32_16x16x32_bf16(kf, qf[kk], sv, 0, 0, 0);
      }
      sf[j] = sv;
    }
    if (tile == qt) {                           // causal mask on diagonal tile
      int q_rel = (w << 4) + lo;
#pragma unroll
      for (int j = 0; j < 4; ++j)
#pragma unroll
        for (int r = 0; r < 4; ++r)
          if (((j << 4) + (hi << 2) + r) > q_rel) sf[j][r] = -1e9f;
    }
    float pmax = sf[0][0];
#pragma unroll
    for (int j = 0; j < 4; ++j)
#pragma unroll
      for (int r = 0; r < 4; ++r) pmax = fmaxf(pmax, sf[j][r]);
    pmax = fmaxf(pmax, __shfl_xor(pmax, 16, 64));
    pmax = fmaxf(pmax, __shfl_xor(pmax, 32, 64));
    if (__any(pmax > mrun + 8.f)) {             // defer-max rescale (THR=8)
      float mn = fmaxf(mrun, pmax);
      float fsc = __expf(mrun - mn);
      mrun = mn;
      lrun *= fsc;
#pragma unroll
      for (int f = 0; f < 8; ++f)
#pragma unroll
        for (int r = 0; r < 4; ++r) acc[f][r] *= fsc;
    }
    float psum = 0.f;
#pragma unroll
    for (int j = 0; j < 4; ++j)
#pragma unroll
      for (int r = 0; r < 4; ++r) {
        float p = __expf(sf[j][r] - mrun);
        sf[j][r] = p;
        psum += p;
      }
    psum += __shfl_xor(psum, 16, 64);
    psum += __shfl_xor(psum, 32, 64);
    lrun += psum;

#pragma unroll
    for (int j = 0; j < 4; ++j) {
      uint2 pk;
      pk.x = cvtpk(sf[j][0], sf[j][1]);
      pk.y = cvtpk(sf[j][2], sf[j][3]);
      *(uint2*)&Pl[w][lo * 72 + (j << 4) + (hi << 2)] = pk;
    }
#pragma unroll
    for (int kk = 0; kk < 2; ++kk) {
      bf16x8 pf = *(const bf16x8*)&Pl[w][lo * 72 + (kk << 5) + (hi << 3)];
#pragma unroll
      for (int f = 0; f < 8; ++f) {
        int vrow = (f << 4) + lo;
        int phys = ((kk << 2) + hi) ^ (vrow & 7);
        bf16x8 vf = *(const bf16x8*)(&Vl[c][0] + vrow * 64 + phys * 8);
        acc[f] = __builtin_amdgcn_mfma_f32_16x16x32_bf16(vf, pf, acc[f], 0, 0, 0);
      }
    }
    __syncthreads();   // one barrier/tile: drains stage(t+1); closes buf reuse
  }

  float rl = 1.0f / lrun;
#pragma unroll
  for (int half = 0; half < 2; ++half) {
#pragma unroll
    for (int f2 = 0; f2 < 4; ++f2) {
      int f = (half << 2) + f2;
      uint2 pk;
      pk.x = cvtpk(acc[f][0] * rl, acc[f][1] * rl);
      pk.y = cvtpk(acc[f][2] * rl, acc[f][3] * rl);
      *(uint2*)&Pl[w][lo * 72 + (f2 << 4) + (hi << 2)] = pk;
    }
#pragma unroll
    for (int it = 0; it < 2; ++it) {
      int rowq = (lane >> 3) + (it << 3);
      int c8 = lane & 7;
      uint4 val = *(const uint4*)&Pl[w][rowq * 72 + c8 * 8];
      *(uint4*)(O + (size_t)(b * S_LEN + (qt << 6) + (w << 4) + rowq) * 4096 +
                h * 128 + (half << 6) + c8 * 8) = val;
    }
  }
}

// ---------------- launch ----------------
extern "C" void kernel_launch(void* const* d_in, const int* in_sizes, int n_in,
                              void* d_out, int out_size, void* d_ws, size_t ws_size,
                              hipStream_t stream) {
  const float* hidden = (const float*)d_in[0];
  const int* pos = (const int*)d_in[1];
  const float* Wq = (const float*)d_in[2];
  const float* Wk = (const float*)d_in[3];
  const float* Wv = (const float*)d_in[4];
  const float* Wo = (const float*)d_in[5];
  float* out = (float*)d_out;

  u16* hb   = (u16*)d_ws;                 // [4096][4096]
  u16* wqb  = hb   + 16777216;            // [4096][4096]  } contiguous -> fused
  u16* wkb  = wqb  + 16777216;            // [1024][4096]  }   B matrix [6144][4096]
  u16* wvb  = wkb  + 4194304;             // [1024][4096]  }
  u16* wob  = wvb  + 4194304;             // [4096][4096]  (cvt AFTER reduce; region
  u16* QKVb = wob  + 16777216;            //   doubles as split-K partial p0 33.5MB)
  u16* Vtb  = QKVb + 25165824;            // [16*128][2048]
  u16* Ob   = Vtb  + 4194304;             // [4096][4096]  (attn output, written after
                                          //   reduce; doubles as partial p1 33.5MB)
  float* part0 = (float*)wob;
  float* part1 = (float*)Ob;

  cvt_f32_bf16<<<8192, 256, 0, stream>>>(hidden, hb, 16777216);
  cvt_f32_bf16<<<8192, 256, 0, stream>>>(Wq, wqb, 16777216);
  cvt_f32_bf16<<<2048, 256, 0, stream>>>(Wk, wkb, 4194304);
  cvt_f32_bf16<<<2048, 256, 0, stream>>>(Wv, wvb, 4194304);

  // QKV round 1: tiles 0-255, full K (1.0 rounds)
  gemm256<1><<<256, 512, 0, stream>>>(hb, wqb, QKVb, 4096, QKV_N, 4096,
                                      0, 0, 0, 0, 64, 0, nullptr, nullptr);
  // QKV round 2: tiles 256-383 x 2 K-halves (256 blocks = 1.0 rounds, NKT=32)
  gemm256<2><<<256, 512, 0, stream>>>(hb, wqb, QKVb, 4096, QKV_N, 4096,
                                      0, 0, 0, 2048, 32, 256, part0, part1);
  reduce_splitk<<<4096, 256, 0, stream>>>(part0, part1, QKVb);

  cvt_f32_bf16<<<8192, 256, 0, stream>>>(Wo, wob, 16777216);  // after reduce freed p0

  rope_kernel<<<8192, 256, 0, stream>>>(QKVb, pos, 4096, QKV_N, 0.08838834764831845f); // Q (pre-scaled)
  rope_kernel<<<2048, 256, 0, stream>>>(QKVb + 4096, pos, 1024, QKV_N, 1.0f);          // K

  transpose_v<<<512, 256, 0, stream>>>(QKVb + 5120, Vtb);

  attn_kernel<<<2048, 256, 0, stream>>>(QKVb, QKVb + 4096, Vtb, Ob);

  // O-proj: MODE0 (fp32 C, XCD map); 256 blocks = 1.0 rounds
  gemm256<0><<<256, 512, 0, stream>>>(Ob, wob, out, 4096, 4096, 4096,
                                      2, 4, 8, 0, 64, 0, nullptr, nullptr);
}

// Round 17
// 496.292 us; speedup vs baseline: 1.3499x; 1.0402x over previous
//
#include <hip/hip_runtime.h>

#define S_LEN 2048
#define BATCH 2
#define HID 4096
#define NH 32
#define NKV 8
#define DH 128
#define MROWS (BATCH*S_LEN)   // 4096
#define QKV_N 6144

typedef unsigned short u16;
typedef unsigned int u32;
typedef __bf16 bf16x8 __attribute__((ext_vector_type(8)));
typedef float f32x4 __attribute__((ext_vector_type(4)));
typedef u16 u16x8 __attribute__((ext_vector_type(8)));

__device__ __forceinline__ u16 f2bf(float f) {           // round-half-up (2 insts)
  union { float f; u32 u; } v; v.f = f;
  return (u16)((v.u + 0x8000u) >> 16);
}
__device__ __forceinline__ float bf2f(u16 h) {
  union { u32 u; float f; } v; v.u = ((u32)h) << 16;
  return v.f;
}
__device__ __forceinline__ u32 cvtpk(float a, float b) { // packs bf16(a)|bf16(b)<<16
  u32 r;
  asm("v_cvt_pk_bf16_f32 %0, %1, %2" : "=v"(r) : "v"(a), "v"(b));
  return r;
}
__device__ __forceinline__ void async16(const void* g, void* l) {
  __builtin_amdgcn_global_load_lds(
      (const __attribute__((address_space(1))) u32*)g,
      (__attribute__((address_space(3))) u32*)l, 16, 0, 0);
}
__device__ __forceinline__ f32x4 mfma16(bf16x8 a, bf16x8 b, f32x4 c) {
  return __builtin_amdgcn_mfma_f32_16x16x32_bf16(a, b, c, 0, 0, 0);
}

#define BAR()    __builtin_amdgcn_s_barrier()
#define LGKM0()  asm volatile("s_waitcnt lgkmcnt(0)" ::: "memory")
#define PRIO(x)  __builtin_amdgcn_s_setprio(x)

// ---------------- fp32 -> bf16 conversion ----------------
__global__ __launch_bounds__(256) void cvt_f32_bf16(const float* __restrict__ in,
                                                    u16* __restrict__ out, int n) {
  int i0 = (blockIdx.x * 256 + threadIdx.x) * 8;
  if (i0 >= n) return;
  float4 a = *(const float4*)(in + i0);
  float4 b = *(const float4*)(in + i0 + 4);
  u16x8 r;
  r[0]=f2bf(a.x); r[1]=f2bf(a.y); r[2]=f2bf(a.z); r[3]=f2bf(a.w);
  r[4]=f2bf(b.x); r[5]=f2bf(b.y); r[6]=f2bf(b.z); r[7]=f2bf(b.w);
  *(u16x8*)(out + i0) = r;
}

// ---------------- 256x256 NT bf16 GEMM (r11 core; MODE + split-K, r16) -----
template<int MODE>
__global__ __launch_bounds__(512, 2) void gemm256(
    const u16* __restrict__ A, const u16* __restrict__ B, void* __restrict__ Cout,
    int M, int N, int K, int XC, int SR, int SC,
    int kSpan, int nkt, int tileBase, float* p0, float* p1) {
  __shared__ u16 As[2][2][64 * 128];   // [parity-buf][128-row half][128x64]
  __shared__ u16 Bs[2][2][64 * 128];
  const int NKT = nkt;
  int bid = (int)blockIdx.x;
  int tm, tn, half = 0, slot = 0;
  if (MODE == 0) {
    int xcd = bid & 7, l = bid >> 3;
    tm = (xcd / XC) * SR + l / SC;
    tn = (xcd % XC) * SC + l % SC;
  } else {
    int nTN = N >> 8;
    int lin;
    if (MODE == 2) { half = bid >> 7; slot = bid & 127; lin = tileBase + slot; }
    else           { lin = tileBase + bid; }
    tm = lin / nTN; tn = lin - tm * nTN;
  }
  const int koff = (MODE == 2) ? half * kSpan : 0;
  int m0 = tm << 8, n0 = tn << 8;
  int t = threadIdx.x;
  int w = t >> 6, lane = t & 63, lo = lane & 15, hi = lane >> 4;
  int wm = w >> 2, wn = w & 3;
  int rbb = (wn & 1) << 6;

  int srow = (w << 3) + (lane >> 3);
  int scol = (lane & 7) << 3;

  auto stageA = [&](int kt, int buf, int h) {
#pragma unroll
    for (int c2 = 0; c2 < 2; ++c2) {
      int row = (c2 << 6) + srow;
      int col = scol ^ ((row & 7) << 3);
      async16(A + (size_t)(m0 + (h << 7) + row) * K + (kt << 6) + koff + col,
              (char*)&As[buf][h][0] + (c2 << 13) + (w << 10));
    }
  };
  auto stageB = [&](int kt, int buf, int h) {
#pragma unroll
    for (int c2 = 0; c2 < 2; ++c2) {
      int row = (c2 << 6) + srow;
      int col = scol ^ ((row & 7) << 3);
      async16(B + (size_t)(n0 + (h << 7) + row) * K + (kt << 6) + koff + col,
              (char*)&Bs[buf][h][0] + (c2 << 13) + (w << 10));
    }
  };

  const f32x4 fz = {0.f, 0.f, 0.f, 0.f};
  f32x4 acc[8][4];
#pragma unroll
  for (int i = 0; i < 8; ++i)
#pragma unroll
    for (int j = 0; j < 4; ++j) acc[i][j] = fz;
  bf16x8 af[4][2], bf0[2][2], bf1[2][2];

  auto rdA = [&](int c, int halfT, bf16x8 (&dst)[4][2]) {
    const u16* Ab = &As[c][wm][0];
#pragma unroll
    for (int mf = 0; mf < 4; ++mf)
#pragma unroll
      for (int ks = 0; ks < 2; ++ks) {
        int ra = (halfT << 6) + (mf << 4) + lo;
        dst[mf][ks] = *(const bf16x8*)(Ab + (ra << 6) +
                      (((ks << 5) + (hi << 3)) ^ ((ra & 7) << 3)));
      }
  };
  auto rdB = [&](int c, int bfrag, bf16x8 (&dst)[2][2]) {
    const u16* Bb = &Bs[c][wn >> 1][0];
#pragma unroll
    for (int nf = 0; nf < 2; ++nf)
#pragma unroll
      for (int ks = 0; ks < 2; ++ks) {
        int rb = rbb + (bfrag << 5) + (nf << 4) + lo;
        dst[nf][ks] = *(const bf16x8*)(Bb + (rb << 6) +
                      (((ks << 5) + (hi << 3)) ^ ((rb & 7) << 3)));
      }
  };
  auto MM = [&](bf16x8 (&a)[4][2], bf16x8 (&b)[2][2], int mo, int no) {
#pragma unroll
    for (int mf = 0; mf < 4; ++mf)
#pragma unroll
      for (int nf = 0; nf < 2; ++nf)
#pragma unroll
        for (int ks = 0; ks < 2; ++ks)
          acc[mo + mf][no + nf] = mfma16(a[mf][ks], b[nf][ks], acc[mo + mf][no + nf]);
  };

#define VM4()    asm volatile("s_waitcnt vmcnt(4)" ::: "memory")
  stageA(0, 0, 0); stageA(0, 0, 1);
  stageB(0, 0, 0); stageB(0, 0, 1);
  stageB(1, 1, 0); stageB(1, 1, 1);
  VM4();
  BAR();

  const int NT = NKT >> 1;
  for (int it = 0; it < NT; ++it) {
    int e = it << 1, o = e + 1;
    int e2 = (e + 2 >= NKT) ? 0 : e + 2;
    int o2 = (o + 2 >= NKT) ? 1 : o + 2;

    rdA(0, 0, af); rdB(0, 0, bf0);
    stageA(o, 1, 0);
    BAR(); LGKM0(); PRIO(1);
    MM(af, bf0, 0, 0);
    PRIO(0); BAR();

    rdB(0, 1, bf1);
    stageA(o, 1, 1);
    BAR(); LGKM0(); PRIO(1);
    MM(af, bf1, 0, 2);
    PRIO(0); BAR();

    rdA(0, 1, af);
    stageB(e2, 0, 0);
    BAR(); LGKM0(); PRIO(1);
    MM(af, bf1, 4, 2);
    PRIO(0); BAR();

    stageB(e2, 0, 1);
    BAR(); PRIO(1);
    MM(af, bf0, 4, 0);
    PRIO(0); VM4(); BAR();

    rdA(1, 0, af); rdB(1, 0, bf0);
    stageA(e2, 0, 0);
    BAR(); LGKM0(); PRIO(1);
    MM(af, bf0, 0, 0);
    PRIO(0); BAR();

    rdB(1, 1, bf1);
    stageA(e2, 0, 1);
    BAR(); LGKM0(); PRIO(1);
    MM(af, bf1, 0, 2);
    PRIO(0); BAR();

    rdA(1, 1, af);
    stageB(o2, 1, 0);
    BAR(); LGKM0(); PRIO(1);
    MM(af, bf1, 4, 2);
    PRIO(0); BAR();

    stageB(o2, 1, 1);
    BAR(); PRIO(1);
    MM(af, bf0, 4, 0);
    PRIO(0); VM4(); BAR();
  }
#undef VM4

  float* dst = (MODE == 2) ? ((half ? p1 : p0) + (size_t)slot * 65536) : nullptr;
#pragma unroll
  for (int mf = 0; mf < 8; ++mf)
#pragma unroll
    for (int nf = 0; nf < 4; ++nf)
#pragma unroll
      for (int r = 0; r < 4; ++r) {
        int r_l = (wm << 7) + (mf << 4) + (hi << 2) + r;
        int c_l = (wn << 6) + (nf << 4) + lo;
        if (MODE == 2) {
          dst[(size_t)r_l * 256 + c_l] = acc[mf][nf][r];
        } else {
          int row = m0 + r_l, col = n0 + c_l;
          if (MODE == 1) ((u16*)Cout)[(size_t)row * N + col] = f2bf(acc[mf][nf][r]);
          else           ((float*)Cout)[(size_t)row * N + col] = acc[mf][nf][r];
        }
      }
}

// ---------------- split-K reduce: QKVb[tile 256+s] = bf16(p0[s] + p1[s]) ----
__global__ __launch_bounds__(256) void reduce_splitk(const float* __restrict__ p0,
                                                     const float* __restrict__ p1,
                                                     u16* __restrict__ C) {
  int g = blockIdx.x * 256 + threadIdx.x;       // 1,048,576 threads x 8 elems
  int s = g >> 13;                              // tile slot 0-127
  int loc = g & 8191;
  int r_l = loc >> 5, c8 = loc & 31;
  int lin = 256 + s;
  int tm = lin / 24, tn = lin - tm * 24;
  size_t off = (size_t)s * 65536 + r_l * 256 + c8 * 8;
  float4 x0 = *(const float4*)(p0 + off);
  float4 x1 = *(const float4*)(p0 + off + 4);
  float4 y0 = *(const float4*)(p1 + off);
  float4 y1 = *(const float4*)(p1 + off + 4);
  u16x8 r;
  r[0]=f2bf(x0.x+y0.x); r[1]=f2bf(x0.y+y0.y); r[2]=f2bf(x0.z+y0.z); r[3]=f2bf(x0.w+y0.w);
  r[4]=f2bf(x1.x+y1.x); r[5]=f2bf(x1.y+y1.y); r[6]=f2bf(x1.z+y1.z); r[7]=f2bf(x1.w+y1.w);
  *(u16x8*)(C + (size_t)(tm * 256 + r_l) * QKV_N + tn * 256 + c8 * 8) = r;
}

// ---------------- RoPE (in-place on bf16, optional output scale) ----------------
__global__ __launch_bounds__(256) void rope_kernel(u16* __restrict__ X,
                                                   const int* __restrict__ pos,
                                                   int ncols, int pitch, float scale) {
  int idx = blockIdx.x * 256 + threadIdx.x;
  int groups = ncols >> 3;
  int m = idx / groups;
  int gi = idx - m * groups;
  if (m >= MROWS) return;
  int head = gi >> 4;
  int d0 = (gi & 15) << 2;
  float p = (float)pos[m];
  u16* base = X + (size_t)m * pitch + head * 128;
  u16 xa[4], xb[4], oa[4], ob[4];
  *(uint2*)xa = *(const uint2*)(base + d0);
  *(uint2*)xb = *(const uint2*)(base + d0 + 64);
#pragma unroll
  for (int i = 0; i < 4; ++i) {
    float j = (float)(d0 + i);
    float inv = __expf(j * -0.14391156516030342f);  // ln(10000)/64
    float fr = p * inv;
    float s, c;
    sincosf(fr, &s, &c);
    float x1 = bf2f(xa[i]), x2 = bf2f(xb[i]);
    oa[i] = f2bf((x1 * c - x2 * s) * scale);
    ob[i] = f2bf((x2 * c + x1 * s) * scale);
  }
  *(uint2*)(base + d0) = *(uint2*)oa;
  *(uint2*)(base + d0 + 64) = *(uint2*)ob;
}

// ---------------- V transpose: QKV[m][5120 + g*128 + d] -> Vt[(b*8+g)*128 + d][s] ----------------
__global__ __launch_bounds__(256) void transpose_v(const u16* __restrict__ V,
                                                   u16* __restrict__ Vt) {
  int bid = blockIdx.x;
  int s0 = (bid & 31) << 6;
  int bg = bid >> 5;
  int b = bg >> 3, g = bg & 7;
  __shared__ u16 tile[64][128];
  int t = threadIdx.x;
#pragma unroll
  for (int r = 0; r < 4; ++r) {
    int c = (r << 8) + t;
    int row = c >> 4, cc = c & 15;
    *(uint4*)&tile[row][cc * 8] =
        *(const uint4*)(V + (size_t)(b * S_LEN + s0 + row) * QKV_N + g * 128 + cc * 8);
  }
  __syncthreads();
#pragma unroll
  for (int r = 0; r < 4; ++r) {
    int c = (r << 8) + t;
    int d = c >> 3, cs = c & 7;
    u16 tmp[8];
#pragma unroll
    for (int i = 0; i < 8; ++i) tmp[i] = tile[cs * 8 + i][d];
    *(uint4*)(Vt + ((size_t)bg * 128 + d) * S_LEN + s0 + cs * 8) = *(uint4*)tmp;
  }
}

// ---------------- Flash attention, r17: QBLK=128, 8 waves, 16 waves/CU -----
// r16 profile: attn 146us, MfmaUtil 21%, VALUBusy 45%, occupancy 21% -> both
// pipes idle = latency/TLP-bound. This kernel: one block = 8 waves x 16 q-rows
// = 128 q-rows sharing each staged K/V tile (staging + barriers per FLOP
// halve), single-buffered K/V -> LDS 50KB -> 2 blocks/CU @ VGPR88 = 16
// waves/CU (2x TLP). Inner wave code identical to r15/r16 (verified QK^T/
// softmax/PV/Pl patterns). Causal mask generalized: tiles t >= 2*qb mask
// (t*64 + k_rel) > (qb*128 + q_rel)  (two partial tiles per block).
// Grid 1024 = 16 q-blocks (heavy-first) x 64 (b,h).
__global__ __launch_bounds__(512) void attn_kernel(
    const u16* __restrict__ Q, const u16* __restrict__ K,
    const u16* __restrict__ Vt, u16* __restrict__ O) {
  int bid = blockIdx.x;
  int qb = 15 - (bid >> 6);          // heavy q-blocks first
  int bh = bid & 63;
  int b = bh >> 5, h = bh & 31;
  int g = h >> 2;
  __shared__ u16 Kl[64 * 128];
  __shared__ u16 Vl[128 * 64];
  __shared__ u16 Pl[8][16 * 72];     // per-wave P^T / O-bounce, pitch 72
  int t = threadIdx.x, w = t >> 6, lane = t & 63, lo = lane & 15, hi = lane >> 4;

  bf16x8 qf[4];   // B-operand: lane -> Q row (q=lo)
  {
    const u16* qb_ = Q + (size_t)(b * S_LEN + (qb << 7) + (w << 4) + lo) * QKV_N + h * 128;
#pragma unroll
    for (int kk = 0; kk < 4; ++kk) qf[kk] = *(const bf16x8*)(qb_ + kk * 32 + hi * 8);
  }
  const f32x4 fz = {0.f, 0.f, 0.f, 0.f};
  f32x4 acc[8];
#pragma unroll
  for (int f = 0; f < 8; ++f) acc[f] = fz;
  float mrun = -1e30f, lrun = 0.f;

  const u16* Kbase = K + (size_t)(b * S_LEN) * QKV_N + g * 128;
  const u16* Vbase = Vt + (size_t)((b << 3) + g) * 128 * S_LEN;

  auto stageKV = [&](int tile) {     // 512 thr: 2 K-chunks + 2 V-chunks each
    int s0 = tile << 6;
#pragma unroll
    for (int r = 0; r < 2; ++r) {              // K tile [64][128], chunk-swizzled
      int c = (r << 9) + t;
      int row = c >> 4, cc = c & 15;
      int src = cc ^ (row & 7);
      async16(Kbase + (size_t)(s0 + row) * QKV_N + src * 8,
              (char*)Kl + (r << 13) + (w << 10));
    }
#pragma unroll
    for (int r = 0; r < 2; ++r) {              // V^T tile [128][64], chunk-swizzled
      int c = (r << 9) + t;
      int row = c >> 3, cc = c & 7;
      int src = cc ^ (row & 7);
      async16(Vbase + (size_t)row * S_LEN + s0 + src * 8,
              (char*)Vl + (r << 13) + (w << 10));
    }
  };

  int ntiles = (qb + 1) << 1;
  int q_glob = (qb << 7) + (w << 4) + lo;      // this lane's global q row (in seq)

  for (int tile = 0; tile < ntiles; ++tile) {
    stageKV(tile);
    __syncthreads();                           // drains stage (implicit vmcnt0)

    f32x4 sf[4];
#pragma unroll
    for (int j = 0; j < 4; ++j) {
      f32x4 sv = fz;
#pragma unroll
      for (int kk = 0; kk < 4; ++kk) {
        int row = (j << 4) + lo;
        int ch = ((kk << 2) + hi) ^ (row & 7);
        bf16x8 kf = *(const bf16x8*)(Kl + row * 128 + ch * 8);
        sv = __builtin_amdgcn_mfma_f32_16x16x32_bf16(kf, qf[kk], sv, 0, 0, 0);
      }
      sf[j] = sv;
    }
    if (tile >= (qb << 1)) {                   // causal mask (2 partial tiles)
      int kbase = tile << 6;
#pragma unroll
      for (int j = 0; j < 4; ++j)
#pragma unroll
        for (int r = 0; r < 4; ++r)
          if ((kbase + (j << 4) + (hi << 2) + r) > q_glob) sf[j][r] = -1e9f;
    }
    float pmax = sf[0][0];
#pragma unroll
    for (int j = 0; j < 4; ++j)
#pragma unroll
      for (int r = 0; r < 4; ++r) pmax = fmaxf(pmax, sf[j][r]);
    pmax = fmaxf(pmax, __shfl_xor(pmax, 16, 64));
    pmax = fmaxf(pmax, __shfl_xor(pmax, 32, 64));
    if (__any(pmax > mrun + 8.f)) {            // defer-max rescale (THR=8)
      float mn = fmaxf(mrun, pmax);
      float fsc = __expf(mrun - mn);
      mrun = mn;
      lrun *= fsc;
#pragma unroll
      for (int f = 0; f < 8; ++f)
#pragma unroll
        for (int r = 0; r < 4; ++r) acc[f][r] *= fsc;
    }
    float psum = 0.f;
#pragma unroll
    for (int j = 0; j < 4; ++j)
#pragma unroll
      for (int r = 0; r < 4; ++r) {
        float p = __expf(sf[j][r] - mrun);
        sf[j][r] = p;
        psum += p;
      }
    psum += __shfl_xor(psum, 16, 64);
    psum += __shfl_xor(psum, 32, 64);
    lrun += psum;

#pragma unroll
    for (int j = 0; j < 4; ++j) {
      uint2 pk;
      pk.x = cvtpk(sf[j][0], sf[j][1]);
      pk.y = cvtpk(sf[j][2], sf[j][3]);
      *(uint2*)&Pl[w][lo * 72 + (j << 4) + (hi << 2)] = pk;
    }
#pragma unroll
    for (int kk = 0; kk < 2; ++kk) {
      bf16x8 pf = *(const bf16x8*)&Pl[w][lo * 72 + (kk << 5) + (hi << 3)];
#pragma unroll
      for (int f = 0; f < 8; ++f) {
        int vrow = (f << 4) + lo;
        int phys = ((kk << 2) + hi) ^ (vrow & 7);
        bf16x8 vf = *(const bf16x8*)(Vl + vrow * 64 + phys * 8);
        acc[f] = __builtin_amdgcn_mfma_f32_16x16x32_bf16(vf, pf, acc[f], 0, 0, 0);
      }
    }
    __syncthreads();                           // buffers consumed; next stage safe
  }

  float rl = 1.0f / lrun;
#pragma unroll
  for (int half = 0; half < 2; ++half) {
#pragma unroll
    for (int f2 = 0; f2 < 4; ++f2) {
      int f = (half << 2) + f2;
      uint2 pk;
      pk.x = cvtpk(acc[f][0] * rl, acc[f][1] * rl);
      pk.y = cvtpk(acc[f][2] * rl, acc[f][3] * rl);
      *(uint2*)&Pl[w][lo * 72 + (f2 << 4) + (hi << 2)] = pk;
    }
#pragma unroll
    for (int it = 0; it < 2; ++it) {
      int rowq = (lane >> 3) + (it << 3);
      int c8 = lane & 7;
      uint4 val = *(const uint4*)&Pl[w][rowq * 72 + c8 * 8];
      *(uint4*)(O + (size_t)(b * S_LEN + (qb << 7) + (w << 4) + rowq) * 4096 +
                h * 128 + (half << 6) + c8 * 8) = val;
    }
  }
}

// ---------------- launch ----------------
extern "C" void kernel_launch(void* const* d_in, const int* in_sizes, int n_in,
                              void* d_out, int out_size, void* d_ws, size_t ws_size,
                              hipStream_t stream) {
  const float* hidden = (const float*)d_in[0];
  const int* pos = (const int*)d_in[1];
  const float* Wq = (const float*)d_in[2];
  const float* Wk = (const float*)d_in[3];
  const float* Wv = (const float*)d_in[4];
  const float* Wo = (const float*)d_in[5];
  float* out = (float*)d_out;

  u16* hb   = (u16*)d_ws;                 // [4096][4096]
  u16* wqb  = hb   + 16777216;            // [4096][4096]  } contiguous -> fused
  u16* wkb  = wqb  + 16777216;            // [1024][4096]  }   B matrix [6144][4096]
  u16* wvb  = wkb  + 4194304;             // [1024][4096]  }
  u16* wob  = wvb  + 4194304;             // [4096][4096]  (cvt AFTER reduce; doubles
  u16* QKVb = wob  + 16777216;            //   as split-K partial p0)
  u16* Vtb  = QKVb + 25165824;            // [16*128][2048]
  u16* Ob   = Vtb  + 4194304;             // [4096][4096]  (doubles as partial p1)
  float* part0 = (float*)wob;
  float* part1 = (float*)Ob;

  cvt_f32_bf16<<<8192, 256, 0, stream>>>(hidden, hb, 16777216);
  cvt_f32_bf16<<<8192, 256, 0, stream>>>(Wq, wqb, 16777216);
  cvt_f32_bf16<<<2048, 256, 0, stream>>>(Wk, wkb, 4194304);
  cvt_f32_bf16<<<2048, 256, 0, stream>>>(Wv, wvb, 4194304);

  // QKV round 1: tiles 0-255, full K (1.0 rounds)
  gemm256<1><<<256, 512, 0, stream>>>(hb, wqb, QKVb, 4096, QKV_N, 4096,
                                      0, 0, 0, 0, 64, 0, nullptr, nullptr);
  // QKV round 2: tiles 256-383 x 2 K-halves (256 blocks = 1.0 rounds, NKT=32)
  gemm256<2><<<256, 512, 0, stream>>>(hb, wqb, QKVb, 4096, QKV_N, 4096,
                                      0, 0, 0, 2048, 32, 256, part0, part1);
  reduce_splitk<<<4096, 256, 0, stream>>>(part0, part1, QKVb);

  cvt_f32_bf16<<<8192, 256, 0, stream>>>(Wo, wob, 16777216);  // after reduce freed p0

  rope_kernel<<<8192, 256, 0, stream>>>(QKVb, pos, 4096, QKV_N, 0.08838834764831845f); // Q (pre-scaled)
  rope_kernel<<<2048, 256, 0, stream>>>(QKVb + 4096, pos, 1024, QKV_N, 1.0f);          // K

  transpose_v<<<512, 256, 0, stream>>>(QKVb + 5120, Vtb);

  // attn: QBLK=128, 8 waves; grid 16 q-blocks x 64 (b,h)
  attn_kernel<<<1024, 512, 0, stream>>>(QKVb, QKVb + 4096, Vtb, Ob);

  // O-proj: MODE0 (fp32 C, XCD map); 256 blocks = 1.0 rounds
  gemm256<0><<<256, 512, 0, stream>>>(Ob, wob, out, 4096, 4096, 4096,
                                      2, 4, 8, 0, 64, 0, nullptr, nullptr);
}